// Round 7
// baseline (538.985 us; speedup 1.0000x reference)
//
#include <hip/hip_runtime.h>
#include <hip/hip_fp16.h>

#define NODES 100000
#define NBKT 782            // ceil(100000/128) buckets of 128 cols
#define HCHUNK 8192         // edges per bucket_hist block
#define FCHUNK 4096         // edges per bucket_fill block (256 thr x 16)

typedef unsigned short u16;
typedef unsigned int u32;

__device__ __forceinline__ float bflo(u32 v) { return __uint_as_float(v << 16); }
__device__ __forceinline__ float bfhi(u32 v) { return __uint_as_float(v & 0xFFFF0000u); }
__device__ __forceinline__ u16 f2bf(float f) {  // RNE
  u32 x = __float_as_uint(f);
  return (u16)((x + 0x7FFFu + ((x >> 16) & 1u)) >> 16);
}

// ---------------- small utils ----------------

__global__ __launch_bounds__(256) void zero_k(int* __restrict__ p, int n) {
  int i = blockIdx.x * 256 + threadIdx.x;
  if (i < n) p[i] = 0;
}

// ---------------- bucket build ----------------

__global__ __launch_bounds__(256) void bucket_hist_k(const int* __restrict__ col,
                                                     int* __restrict__ bcnt, int E) {
  __shared__ int h[NBKT];
  int t = threadIdx.x;
  for (int i = t; i < NBKT; i += 256) h[i] = 0;
  __syncthreads();
  int base = blockIdx.x * HCHUNK;
#pragma unroll 4
  for (int j = 0; j < HCHUNK / 256; ++j) {
    int i = base + j * 256 + t;
    if (i < E) atomicAdd(&h[col[i] >> 7], 1);
  }
  __syncthreads();
  for (int i = t; i < NBKT; i += 256) {
    int c = h[i];
    if (c) atomicAdd(&bcnt[i], c);
  }
}

__global__ __launch_bounds__(256) void bscan_k(const int* __restrict__ bcnt,
                                               int* __restrict__ boffs,
                                               int* __restrict__ bcurs, int nb, int E) {
  __shared__ int lds[256];
  int t = threadIdx.x;
  int base = t * 4;
  int v[4];
#pragma unroll
  for (int j = 0; j < 4; ++j) v[j] = (base + j < nb) ? bcnt[base + j] : 0;
  int s = v[0] + v[1] + v[2] + v[3];
  lds[t] = s;
  __syncthreads();
  for (int off = 1; off < 256; off <<= 1) {
    int y = (t >= off) ? lds[t - off] : 0;
    __syncthreads();
    lds[t] += y;
    __syncthreads();
  }
  int excl = lds[t] - s;
#pragma unroll
  for (int j = 0; j < 4; ++j) {
    int i = base + j;
    if (i < nb) { boffs[i] = excl; bcurs[i] = excl; }
    excl += v[j];
  }
  if (t == 255) boffs[nb] = E;
}

// scatter packed records (colLow<<17 | row) into bucket regions.
__global__ __launch_bounds__(256) void bucket_fill_k(const int* __restrict__ row,
                                                     const int* __restrict__ col,
                                                     int* __restrict__ bcurs,
                                                     u32* __restrict__ recs, int E) {
  __shared__ int lcnt[NBKT];
  __shared__ int lbase[NBKT];
  int t = threadIdx.x;
  int base = blockIdx.x * FCHUNK;
  for (int i = t; i < NBKT; i += 256) lcnt[i] = 0;
  __syncthreads();
  u32 rec[FCHUNK / 256];
  u32 meta[FCHUNK / 256];
#pragma unroll
  for (int j = 0; j < FCHUNK / 256; ++j) {
    int i = base + j * 256 + t;
    if (i < E) {
      int r = row[i], c = col[i];
      int b = c >> 7;
      rec[j] = (u32)r | ((u32)(c & 127) << 17);
      int lr = atomicAdd(&lcnt[b], 1);
      meta[j] = (u32)lr | ((u32)b << 16);
    } else {
      meta[j] = 0xFFFFFFFFu;
    }
  }
  __syncthreads();
  for (int i = t; i < NBKT; i += 256) {
    int c = lcnt[i];
    lbase[i] = c ? atomicAdd(&bcurs[i], c) : 0;
  }
  __syncthreads();
#pragma unroll
  for (int j = 0; j < FCHUNK / 256; ++j) {
    if (meta[j] != 0xFFFFFFFFu) {
      int b = meta[j] >> 16;
      int lr = meta[j] & 0xFFFF;
      recs[lbase[b] + lr] = rec[j];
    }
  }
}

// records (bucketed by col) -> per-node CSR (offs, adj) + dis. One block per bucket.
__global__ __launch_bounds__(256) void csr_k(const u32* __restrict__ recs,
                                             const int* __restrict__ boffs,
                                             int* __restrict__ offs, int* __restrict__ adj,
                                             float* __restrict__ dis, int N, int E) {
  __shared__ int cnt[128];
  __shared__ int sa[128], sb[128];
  __shared__ int cur[128];
  int b = blockIdx.x, t = threadIdx.x;
  if (t < 128) cnt[t] = 0;
  __syncthreads();
  int s = boffs[b], e = boffs[b + 1];
  for (int i = s + t; i < e; i += 256) atomicAdd(&cnt[recs[i] >> 17], 1);
  __syncthreads();
  if (t < 128) sa[t] = cnt[t];
  __syncthreads();
#pragma unroll
  for (int off = 1; off < 128; off <<= 1) {
    if (t < 128) sb[t] = sa[t] + ((t >= off) ? sa[t - off] : 0);
    __syncthreads();
    if (t < 128) sa[t] = sb[t];
    __syncthreads();
  }
  if (t < 128) {
    int c = b * 128 + t;
    if (c < N) {
      int excl = sa[t] - cnt[t];
      offs[c] = s + excl;
      cur[t] = s + excl;
      dis[c] = rsqrtf((float)(cnt[t] + 1));  // +1 self loop
    }
  }
  if (b == 0 && t == 0) offs[N] = E;
  __syncthreads();
  for (int i = s + t; i < e; i += 256) {
    u32 r = recs[i];
    int p = atomicAdd(&cur[r >> 17], 1);
    adj[p] = (int)(r & 0x1FFFF);
  }
}

// ---------------- GEMM: G[node,:] = (X[node,:] @ W) * dis[node] ----------------
// One wave per block, thread = node, acc[NOUT] in VGPR.
// W[k*NOUT+j] is wave-uniform -> s_load + v_fmac with SGPR operand (no LDS for W).
// KP: LDS row stride for X (KP%4==0 for float4 staging; KP%32==4 keeps ds_read_b32
// at 8-way, ~17cy vs 2*NOUT cy FMA per k -> negligible).
// OUTFMT: 1 = bf16 out, 2 = fp16 out.
template <int K, int KP, int NOUT, int OUTFMT>
__global__ __launch_bounds__(64) void gemm_sw_k(const float* __restrict__ X,
                                                const float* __restrict__ W,
                                                const float* __restrict__ dis,
                                                u16* __restrict__ G, int n) {
  __shared__ float Xs[64 * KP];
  int t = threadIdx.x;
  int b0 = blockIdx.x * 64;
  // stage X tile (coalesced float4)
  constexpr int NF4 = K / 4;
  const float4* X4 = (const float4*)X;
  int base4 = b0 * NF4;
  int lim4 = (n * K) >> 2;
  for (int i = t; i < 64 * NF4; i += 64) {
    float4 v = {0.f, 0.f, 0.f, 0.f};
    if (base4 + i < lim4) v = X4[base4 + i];
    int r = i / NF4, c4 = i - r * NF4;
    ((float4*)Xs)[r * (KP / 4) + c4] = v;
  }
  __syncthreads();

  float acc[NOUT];
#pragma unroll
  for (int j = 0; j < NOUT; ++j) acc[j] = 0.f;
  const float* xr = &Xs[t * KP];
#pragma unroll 2
  for (int k = 0; k < K; ++k) {
    float a = xr[k];
#pragma unroll
    for (int j = 0; j < NOUT; ++j) acc[j] = fmaf(a, W[k * NOUT + j], acc[j]);
  }

  __syncthreads();  // done with Xs as input tile; reuse as store staging
  int node = b0 + t;
  float sc = (node < n) ? dis[node] : 0.f;
  if (NOUT == 64) {
    u32* os = (u32*)Xs;  // [64][33] padded
#pragma unroll
    for (int j = 0; j < 32; ++j) {
      float v0 = acc[2 * j] * sc, v1 = acc[2 * j + 1] * sc;
      u16 lo, hi;
      if (OUTFMT == 1) { lo = f2bf(v0); hi = f2bf(v1); }
      else { lo = __half_as_ushort(__float2half(v0)); hi = __half_as_ushort(__float2half(v1)); }
      os[t * 33 + j] = (u32)lo | ((u32)hi << 16);
    }
    __syncthreads();
    u32* G32 = (u32*)G;
    for (int idx = t; idx < 64 * 32; idx += 64) {
      int r = idx >> 5;
      if (b0 + r < n) G32[(size_t)b0 * 32 + idx] = os[r * 33 + (idx & 31)];
    }
  } else {
    u16* s16 = (u16*)Xs;
#pragma unroll
    for (int j = 0; j < NOUT; ++j) {
      float v = acc[j] * sc;
      s16[t * NOUT + j] = (OUTFMT == 1) ? f2bf(v) : __half_as_ushort(__float2half(v));
    }
    __syncthreads();
    int nn = n - b0; if (nn > 64) nn = 64;
    int lim2 = nn * NOUT;
    for (int idx = t; idx < lim2; idx += 64) G[(size_t)b0 * NOUT + idx] = s16[idx];
  }
}

// ---------------- aggregation (hidden): 2 edges per wave-gather, 16 edges in flight ----------------
__global__ __launch_bounds__(256) void agg_bf16_k(const u16* __restrict__ g,
                                                  const int* __restrict__ offs,
                                                  const int* __restrict__ adj,
                                                  const float* __restrict__ dis,
                                                  const float* __restrict__ bias,
                                                  float* __restrict__ out, int n) {
  int node = blockIdx.x * 4 + (threadIdx.x >> 6);
  int lane = threadIdx.x & 63;
  int half = lane >> 5, fl = lane & 31;
  if (node >= n) return;
  const u32* g32 = (const u32*)g;
  float acc0 = 0.f, acc1 = 0.f;
  int s = offs[node], e = offs[node + 1];
  int i = s;
  for (; i + 16 <= e; i += 16) {  // 8 gathers in flight per lane
    int r0 = adj[i + half];
    int r1 = adj[i + 2 + half];
    int r2 = adj[i + 4 + half];
    int r3 = adj[i + 6 + half];
    int r4 = adj[i + 8 + half];
    int r5 = adj[i + 10 + half];
    int r6 = adj[i + 12 + half];
    int r7 = adj[i + 14 + half];
    u32 v0 = g32[(r0 << 5) + fl];
    u32 v1 = g32[(r1 << 5) + fl];
    u32 v2 = g32[(r2 << 5) + fl];
    u32 v3 = g32[(r3 << 5) + fl];
    u32 v4 = g32[(r4 << 5) + fl];
    u32 v5 = g32[(r5 << 5) + fl];
    u32 v6 = g32[(r6 << 5) + fl];
    u32 v7 = g32[(r7 << 5) + fl];
    acc0 += ((bflo(v0) + bflo(v1)) + (bflo(v2) + bflo(v3))) +
            ((bflo(v4) + bflo(v5)) + (bflo(v6) + bflo(v7)));
    acc1 += ((bfhi(v0) + bfhi(v1)) + (bfhi(v2) + bfhi(v3))) +
            ((bfhi(v4) + bfhi(v5)) + (bfhi(v6) + bfhi(v7)));
  }
  for (; i + 8 <= e; i += 8) {
    int r0 = adj[i + half];
    int r1 = adj[i + 2 + half];
    int r2 = adj[i + 4 + half];
    int r3 = adj[i + 6 + half];
    u32 v0 = g32[(r0 << 5) + fl];
    u32 v1 = g32[(r1 << 5) + fl];
    u32 v2 = g32[(r2 << 5) + fl];
    u32 v3 = g32[(r3 << 5) + fl];
    acc0 += (bflo(v0) + bflo(v1)) + (bflo(v2) + bflo(v3));
    acc1 += (bfhi(v0) + bfhi(v1)) + (bfhi(v2) + bfhi(v3));
  }
  for (; i + 2 <= e; i += 2) {
    int r = adj[i + half];
    u32 v = g32[(r << 5) + fl];
    acc0 += bflo(v);
    acc1 += bfhi(v);
  }
  if (i < e) {  // odd tail edge: only half 0 counts it
    int r = adj[i];
    u32 v = g32[(r << 5) + fl];
    if (half == 0) { acc0 += bflo(v); acc1 += bfhi(v); }
  }
  acc0 += __shfl_xor(acc0, 32, 64);
  acc1 += __shfl_xor(acc1, 32, 64);
  u32 vs = g32[(node << 5) + fl];  // self loop (pre-scaled by dis[node])
  acc0 += bflo(vs);
  acc1 += bfhi(vs);
  float d = dis[node];
  float o0 = fmaxf(fmaf(d, acc0, bias[2 * fl]), 0.f);
  float o1 = fmaxf(fmaf(d, acc1, bias[2 * fl + 1]), 0.f);
  if (half == 0) {
    float2 st = {o0, o1};
    *(float2*)(out + node * 64 + 2 * fl) = st;
  }
}

// ---------------- aggregation (final, 18-wide fp16 table): 2 edges/gather, 16 in flight ----------------
__global__ __launch_bounds__(256) void agg_f16o_k(const u16* __restrict__ g,
                                                  const int* __restrict__ offs,
                                                  const int* __restrict__ adj,
                                                  const float* __restrict__ dis,
                                                  const float* __restrict__ bias,
                                                  float* __restrict__ out, int n) {
  int node = blockIdx.x * 4 + (threadIdx.x >> 6);
  int lane = threadIdx.x & 63;
  int half = lane >> 5, fl = lane & 31;
  if (node >= n) return;
  const __half* gh = (const __half*)g;
  bool act = fl < 18;
  float acc = 0.f;
  int s = offs[node], e = offs[node + 1];
  int i = s;
  if (act) {
    for (; i + 16 <= e; i += 16) {
      int r0 = adj[i + half];
      int r1 = adj[i + 2 + half];
      int r2 = adj[i + 4 + half];
      int r3 = adj[i + 6 + half];
      int r4 = adj[i + 8 + half];
      int r5 = adj[i + 10 + half];
      int r6 = adj[i + 12 + half];
      int r7 = adj[i + 14 + half];
      float a0 = __half2float(gh[r0 * 18 + fl]);
      float a1 = __half2float(gh[r1 * 18 + fl]);
      float a2 = __half2float(gh[r2 * 18 + fl]);
      float a3 = __half2float(gh[r3 * 18 + fl]);
      float a4 = __half2float(gh[r4 * 18 + fl]);
      float a5 = __half2float(gh[r5 * 18 + fl]);
      float a6 = __half2float(gh[r6 * 18 + fl]);
      float a7 = __half2float(gh[r7 * 18 + fl]);
      acc += ((a0 + a1) + (a2 + a3)) + ((a4 + a5) + (a6 + a7));
    }
    for (; i + 8 <= e; i += 8) {
      int r0 = adj[i + half];
      int r1 = adj[i + 2 + half];
      int r2 = adj[i + 4 + half];
      int r3 = adj[i + 6 + half];
      float a0 = __half2float(gh[r0 * 18 + fl]);
      float a1 = __half2float(gh[r1 * 18 + fl]);
      float a2 = __half2float(gh[r2 * 18 + fl]);
      float a3 = __half2float(gh[r3 * 18 + fl]);
      acc += (a0 + a1) + (a2 + a3);
    }
    for (; i + 2 <= e; i += 2) acc += __half2float(gh[adj[i + half] * 18 + fl]);
    if (i < e && half == 0) acc += __half2float(gh[adj[i] * 18 + fl]);
  }
  acc += __shfl_xor(acc, 32, 64);  // all 64 lanes participate
  if (act) {
    acc += __half2float(gh[node * 18 + fl]);  // self loop
    float v = fmaf(dis[node], acc, bias[fl]);
    if (half == 0) out[node * 18 + fl] = v;
  }
}

// ---------------- launch ----------------

extern "C" void kernel_launch(void* const* d_in, const int* in_sizes, int n_in,
                              void* d_out, int out_size, void* d_ws, size_t ws_size,
                              hipStream_t stream) {
  const float* x  = (const float*)d_in[0];
  const int*   ei = (const int*)d_in[1];
  const float* W1 = (const float*)d_in[2];
  const float* b1 = (const float*)d_in[3];
  const float* W2 = (const float*)d_in[4];
  const float* b2 = (const float*)d_in[5];
  const float* W3 = (const float*)d_in[6];
  const float* b3 = (const float*)d_in[7];
  const float* Wo = (const float*)d_in[8];
  const float* bo = (const float*)d_in[9];
  float* out = (float*)d_out;

  const int N = NODES;
  const int E = in_sizes[1] / 2;
  const int* rowp = ei;
  const int* colp = ei + E;

  char* p = (char*)d_ws;
  auto alloc = [&](size_t bytes) {
    void* r = (void*)p;
    p += (bytes + 255) & ~(size_t)255;
    return r;
  };
  int*   bcnt  = (int*)alloc((size_t)NBKT * 4);
  int*   bcurs = (int*)alloc((size_t)NBKT * 4);
  int*   boffs = (int*)alloc((size_t)(NBKT + 1) * 4);
  float* dis   = (float*)alloc((size_t)N * 4);
  int*   offs  = (int*)alloc((size_t)(N + 1) * 4);
  int*   adj   = (int*)alloc((size_t)E * 4);
  // recs (E*4 = 12.8MB) dead after csr_k; alias with bf16 gather table (N*64*2 = 12.8MB)
  u32*   recs  = (u32*)alloc((size_t)N * 64 * 2);
  u16*   gb    = (u16*)recs;
  float* h     = (float*)alloc((size_t)N * 64 * 4);   // fp32 hidden activations
  u16*   g4    = (u16*)alloc((size_t)N * 18 * 2);    // fp16 gather table, final layer

  zero_k<<<(NBKT + 255) / 256, 256, 0, stream>>>(bcnt, NBKT);
  bucket_hist_k<<<(E + HCHUNK - 1) / HCHUNK, 256, 0, stream>>>(colp, bcnt, E);
  bscan_k<<<1, 256, 0, stream>>>(bcnt, boffs, bcurs, NBKT, E);
  bucket_fill_k<<<(E + FCHUNK - 1) / FCHUNK, 256, 0, stream>>>(rowp, colp, bcurs, recs, E);
  csr_k<<<NBKT, 256, 0, stream>>>(recs, boffs, offs, adj, dis, N, E);

  int gG = (N + 63) / 64;
  int gA = (N + 3) / 4;

  gemm_sw_k<100, 100, 64, 1><<<gG, 64, 0, stream>>>(x, W1, dis, gb, N);
  agg_bf16_k<<<gA, 256, 0, stream>>>(gb, offs, adj, dis, b1, h, N);

  gemm_sw_k<64, 68, 64, 1><<<gG, 64, 0, stream>>>(h, W2, dis, gb, N);
  agg_bf16_k<<<gA, 256, 0, stream>>>(gb, offs, adj, dis, b2, h, N);

  gemm_sw_k<64, 68, 64, 1><<<gG, 64, 0, stream>>>(h, W3, dis, gb, N);
  agg_bf16_k<<<gA, 256, 0, stream>>>(gb, offs, adj, dis, b3, h, N);

  gemm_sw_k<64, 68, 18, 2><<<gG, 64, 0, stream>>>(h, Wo, dis, g4, N);
  agg_f16o_k<<<gA, 256, 0, stream>>>(g4, offs, adj, dis, bo, out, N);
}

// Round 8
// 497.176 us; speedup vs baseline: 1.0841x; 1.0841x over previous
//
#include <hip/hip_runtime.h>
#include <hip/hip_fp16.h>

#define NODES 100000
#define NBKT 782            // ceil(100000/128) buckets of 128 cols
#define HCHUNK 8192         // edges per bucket_hist block
#define FCHUNK 4096         // edges per bucket_fill block (256 thr x 16)

typedef unsigned short u16;
typedef unsigned int u32;

__device__ __forceinline__ float bflo(u32 v) { return __uint_as_float(v << 16); }
__device__ __forceinline__ float bfhi(u32 v) { return __uint_as_float(v & 0xFFFF0000u); }
__device__ __forceinline__ u16 f2bf(float f) {  // RNE
  u32 x = __float_as_uint(f);
  return (u16)((x + 0x7FFFu + ((x >> 16) & 1u)) >> 16);
}

// ---------------- small utils ----------------

__global__ __launch_bounds__(256) void zero_k(int* __restrict__ p, int n) {
  int i = blockIdx.x * 256 + threadIdx.x;
  if (i < n) p[i] = 0;
}

// ---------------- bucket build ----------------

__global__ __launch_bounds__(256) void bucket_hist_k(const int* __restrict__ col,
                                                     int* __restrict__ bcnt, int E) {
  __shared__ int h[NBKT];
  int t = threadIdx.x;
  for (int i = t; i < NBKT; i += 256) h[i] = 0;
  __syncthreads();
  int base = blockIdx.x * HCHUNK;
#pragma unroll 4
  for (int j = 0; j < HCHUNK / 256; ++j) {
    int i = base + j * 256 + t;
    if (i < E) atomicAdd(&h[col[i] >> 7], 1);
  }
  __syncthreads();
  for (int i = t; i < NBKT; i += 256) {
    int c = h[i];
    if (c) atomicAdd(&bcnt[i], c);
  }
}

__global__ __launch_bounds__(256) void bscan_k(const int* __restrict__ bcnt,
                                               int* __restrict__ boffs,
                                               int* __restrict__ bcurs, int nb, int E) {
  __shared__ int lds[256];
  int t = threadIdx.x;
  int base = t * 4;
  int v[4];
#pragma unroll
  for (int j = 0; j < 4; ++j) v[j] = (base + j < nb) ? bcnt[base + j] : 0;
  int s = v[0] + v[1] + v[2] + v[3];
  lds[t] = s;
  __syncthreads();
  for (int off = 1; off < 256; off <<= 1) {
    int y = (t >= off) ? lds[t - off] : 0;
    __syncthreads();
    lds[t] += y;
    __syncthreads();
  }
  int excl = lds[t] - s;
#pragma unroll
  for (int j = 0; j < 4; ++j) {
    int i = base + j;
    if (i < nb) { boffs[i] = excl; bcurs[i] = excl; }
    excl += v[j];
  }
  if (t == 255) boffs[nb] = E;
}

// scatter packed records (colLow<<17 | row) into bucket regions.
__global__ __launch_bounds__(256) void bucket_fill_k(const int* __restrict__ row,
                                                     const int* __restrict__ col,
                                                     int* __restrict__ bcurs,
                                                     u32* __restrict__ recs, int E) {
  __shared__ int lcnt[NBKT];
  __shared__ int lbase[NBKT];
  int t = threadIdx.x;
  int base = blockIdx.x * FCHUNK;
  for (int i = t; i < NBKT; i += 256) lcnt[i] = 0;
  __syncthreads();
  u32 rec[FCHUNK / 256];
  u32 meta[FCHUNK / 256];
#pragma unroll
  for (int j = 0; j < FCHUNK / 256; ++j) {
    int i = base + j * 256 + t;
    if (i < E) {
      int r = row[i], c = col[i];
      int b = c >> 7;
      rec[j] = (u32)r | ((u32)(c & 127) << 17);
      int lr = atomicAdd(&lcnt[b], 1);
      meta[j] = (u32)lr | ((u32)b << 16);
    } else {
      meta[j] = 0xFFFFFFFFu;
    }
  }
  __syncthreads();
  for (int i = t; i < NBKT; i += 256) {
    int c = lcnt[i];
    lbase[i] = c ? atomicAdd(&bcurs[i], c) : 0;
  }
  __syncthreads();
#pragma unroll
  for (int j = 0; j < FCHUNK / 256; ++j) {
    if (meta[j] != 0xFFFFFFFFu) {
      int b = meta[j] >> 16;
      int lr = meta[j] & 0xFFFF;
      recs[lbase[b] + lr] = rec[j];
    }
  }
}

// records (bucketed by col) -> per-node CSR (offs, adj) + dis. One block per bucket.
__global__ __launch_bounds__(256) void csr_k(const u32* __restrict__ recs,
                                             const int* __restrict__ boffs,
                                             int* __restrict__ offs, int* __restrict__ adj,
                                             float* __restrict__ dis, int N, int E) {
  __shared__ int cnt[128];
  __shared__ int sa[128], sb[128];
  __shared__ int cur[128];
  int b = blockIdx.x, t = threadIdx.x;
  if (t < 128) cnt[t] = 0;
  __syncthreads();
  int s = boffs[b], e = boffs[b + 1];
  for (int i = s + t; i < e; i += 256) atomicAdd(&cnt[recs[i] >> 17], 1);
  __syncthreads();
  if (t < 128) sa[t] = cnt[t];
  __syncthreads();
#pragma unroll
  for (int off = 1; off < 128; off <<= 1) {
    if (t < 128) sb[t] = sa[t] + ((t >= off) ? sa[t - off] : 0);
    __syncthreads();
    if (t < 128) sa[t] = sb[t];
    __syncthreads();
  }
  if (t < 128) {
    int c = b * 128 + t;
    if (c < N) {
      int excl = sa[t] - cnt[t];
      offs[c] = s + excl;
      cur[t] = s + excl;
      dis[c] = rsqrtf((float)(cnt[t] + 1));  // +1 self loop
    }
  }
  if (b == 0 && t == 0) offs[N] = E;
  __syncthreads();
  for (int i = s + t; i < e; i += 256) {
    u32 r = recs[i];
    int p = atomicAdd(&cur[r >> 17], 1);
    adj[p] = (int)(r & 0x1FFFF);
  }
}

// ---------------- GEMM: G[node,:] = (X[node,:] @ W) * dis[node] ----------------
// thread = node; X row chunk in VGPRs (float4 loads, no LDS, no syncs);
// W[(kc+kk)*NOUT+j] is wave-uniform -> scalar path (s_load + SGPR-operand FMA).
// OUTFMT: 1 = bf16 out, 2 = fp16 out.
template <int K, int CHUNK, int NOUT, int OUTFMT>
__global__ __launch_bounds__(256) void gemm_reg_k(const float* __restrict__ X,
                                                  const float* __restrict__ W,
                                                  const float* __restrict__ dis,
                                                  u16* __restrict__ G, int n) {
  static_assert(K % CHUNK == 0 && CHUNK % 4 == 0, "chunking");
  int node = blockIdx.x * 256 + threadIdx.x;
  bool live = node < n;
  int cn = live ? node : 0;
  const float* xrow = X + (size_t)cn * K;
  float acc[NOUT];
#pragma unroll
  for (int j = 0; j < NOUT; ++j) acc[j] = 0.f;
  for (int kc = 0; kc < K; kc += CHUNK) {
    float xv[CHUNK];
#pragma unroll
    for (int q = 0; q < CHUNK / 4; ++q)
      *(float4*)&xv[4 * q] = *(const float4*)(xrow + kc + 4 * q);
#pragma unroll
    for (int kk = 0; kk < CHUNK; ++kk) {
      float a = xv[kk];
      const float* wr = W + (size_t)(kc + kk) * NOUT;
#pragma unroll
      for (int j = 0; j < NOUT; ++j) acc[j] = fmaf(a, wr[j], acc[j]);
    }
  }
  if (!live) return;
  float sc = dis[node];
  if (NOUT == 64) {
    u32 os[32];
#pragma unroll
    for (int j = 0; j < 32; ++j) {
      float v0 = acc[2 * j] * sc, v1 = acc[2 * j + 1] * sc;
      u16 lo = (OUTFMT == 1) ? f2bf(v0) : __half_as_ushort(__float2half(v0));
      u16 hi = (OUTFMT == 1) ? f2bf(v1) : __half_as_ushort(__float2half(v1));
      os[j] = (u32)lo | ((u32)hi << 16);
    }
    uint4* G4 = (uint4*)G;  // row = 128B = 8 x uint4
#pragma unroll
    for (int q = 0; q < 8; ++q)
      G4[(size_t)node * 8 + q] = make_uint4(os[4 * q], os[4 * q + 1], os[4 * q + 2], os[4 * q + 3]);
  } else {  // NOUT == 18 (fp16), row = 36B = 9 x u32
    u32 os[9];
#pragma unroll
    for (int j = 0; j < 9; ++j) {
      float v0 = acc[2 * j] * sc, v1 = acc[2 * j + 1] * sc;
      u16 lo = __half_as_ushort(__float2half(v0));
      u16 hi = __half_as_ushort(__float2half(v1));
      os[j] = (u32)lo | ((u32)hi << 16);
    }
    u32* G32 = (u32*)G;
#pragma unroll
    for (int j = 0; j < 9; ++j) G32[(size_t)node * 9 + j] = os[j];
  }
}

// ---------------- aggregation (hidden): 2 edges per wave-gather, 16 edges in flight ----------------
__global__ __launch_bounds__(256) void agg_bf16_k(const u16* __restrict__ g,
                                                  const int* __restrict__ offs,
                                                  const int* __restrict__ adj,
                                                  const float* __restrict__ dis,
                                                  const float* __restrict__ bias,
                                                  float* __restrict__ out, int n) {
  int node = blockIdx.x * 4 + (threadIdx.x >> 6);
  int lane = threadIdx.x & 63;
  int half = lane >> 5, fl = lane & 31;
  if (node >= n) return;
  const u32* g32 = (const u32*)g;
  float acc0 = 0.f, acc1 = 0.f;
  int s = offs[node], e = offs[node + 1];
  int i = s;
  for (; i + 16 <= e; i += 16) {  // 8 gathers in flight per lane
    int r0 = adj[i + half];
    int r1 = adj[i + 2 + half];
    int r2 = adj[i + 4 + half];
    int r3 = adj[i + 6 + half];
    int r4 = adj[i + 8 + half];
    int r5 = adj[i + 10 + half];
    int r6 = adj[i + 12 + half];
    int r7 = adj[i + 14 + half];
    u32 v0 = g32[(r0 << 5) + fl];
    u32 v1 = g32[(r1 << 5) + fl];
    u32 v2 = g32[(r2 << 5) + fl];
    u32 v3 = g32[(r3 << 5) + fl];
    u32 v4 = g32[(r4 << 5) + fl];
    u32 v5 = g32[(r5 << 5) + fl];
    u32 v6 = g32[(r6 << 5) + fl];
    u32 v7 = g32[(r7 << 5) + fl];
    acc0 += ((bflo(v0) + bflo(v1)) + (bflo(v2) + bflo(v3))) +
            ((bflo(v4) + bflo(v5)) + (bflo(v6) + bflo(v7)));
    acc1 += ((bfhi(v0) + bfhi(v1)) + (bfhi(v2) + bfhi(v3))) +
            ((bfhi(v4) + bfhi(v5)) + (bfhi(v6) + bfhi(v7)));
  }
  for (; i + 8 <= e; i += 8) {
    int r0 = adj[i + half];
    int r1 = adj[i + 2 + half];
    int r2 = adj[i + 4 + half];
    int r3 = adj[i + 6 + half];
    u32 v0 = g32[(r0 << 5) + fl];
    u32 v1 = g32[(r1 << 5) + fl];
    u32 v2 = g32[(r2 << 5) + fl];
    u32 v3 = g32[(r3 << 5) + fl];
    acc0 += (bflo(v0) + bflo(v1)) + (bflo(v2) + bflo(v3));
    acc1 += (bfhi(v0) + bfhi(v1)) + (bfhi(v2) + bfhi(v3));
  }
  for (; i + 2 <= e; i += 2) {
    int r = adj[i + half];
    u32 v = g32[(r << 5) + fl];
    acc0 += bflo(v);
    acc1 += bfhi(v);
  }
  if (i < e) {  // odd tail edge: only half 0 counts it
    int r = adj[i];
    u32 v = g32[(r << 5) + fl];
    if (half == 0) { acc0 += bflo(v); acc1 += bfhi(v); }
  }
  acc0 += __shfl_xor(acc0, 32, 64);
  acc1 += __shfl_xor(acc1, 32, 64);
  u32 vs = g32[(node << 5) + fl];  // self loop (pre-scaled by dis[node])
  acc0 += bflo(vs);
  acc1 += bfhi(vs);
  float d = dis[node];
  float o0 = fmaxf(fmaf(d, acc0, bias[2 * fl]), 0.f);
  float o1 = fmaxf(fmaf(d, acc1, bias[2 * fl + 1]), 0.f);
  if (half == 0) {
    float2 st = {o0, o1};
    *(float2*)(out + node * 64 + 2 * fl) = st;
  }
}

// ---------------- aggregation (final, 18-wide fp16 table): 2 edges/gather, 16 in flight ----------------
__global__ __launch_bounds__(256) void agg_f16o_k(const u16* __restrict__ g,
                                                  const int* __restrict__ offs,
                                                  const int* __restrict__ adj,
                                                  const float* __restrict__ dis,
                                                  const float* __restrict__ bias,
                                                  float* __restrict__ out, int n) {
  int node = blockIdx.x * 4 + (threadIdx.x >> 6);
  int lane = threadIdx.x & 63;
  int half = lane >> 5, fl = lane & 31;
  if (node >= n) return;
  const __half* gh = (const __half*)g;
  bool act = fl < 18;
  float acc = 0.f;
  int s = offs[node], e = offs[node + 1];
  int i = s;
  if (act) {
    for (; i + 16 <= e; i += 16) {
      int r0 = adj[i + half];
      int r1 = adj[i + 2 + half];
      int r2 = adj[i + 4 + half];
      int r3 = adj[i + 6 + half];
      int r4 = adj[i + 8 + half];
      int r5 = adj[i + 10 + half];
      int r6 = adj[i + 12 + half];
      int r7 = adj[i + 14 + half];
      float a0 = __half2float(gh[r0 * 18 + fl]);
      float a1 = __half2float(gh[r1 * 18 + fl]);
      float a2 = __half2float(gh[r2 * 18 + fl]);
      float a3 = __half2float(gh[r3 * 18 + fl]);
      float a4 = __half2float(gh[r4 * 18 + fl]);
      float a5 = __half2float(gh[r5 * 18 + fl]);
      float a6 = __half2float(gh[r6 * 18 + fl]);
      float a7 = __half2float(gh[r7 * 18 + fl]);
      acc += ((a0 + a1) + (a2 + a3)) + ((a4 + a5) + (a6 + a7));
    }
    for (; i + 8 <= e; i += 8) {
      int r0 = adj[i + half];
      int r1 = adj[i + 2 + half];
      int r2 = adj[i + 4 + half];
      int r3 = adj[i + 6 + half];
      float a0 = __half2float(gh[r0 * 18 + fl]);
      float a1 = __half2float(gh[r1 * 18 + fl]);
      float a2 = __half2float(gh[r2 * 18 + fl]);
      float a3 = __half2float(gh[r3 * 18 + fl]);
      acc += (a0 + a1) + (a2 + a3);
    }
    for (; i + 2 <= e; i += 2) acc += __half2float(gh[adj[i + half] * 18 + fl]);
    if (i < e && half == 0) acc += __half2float(gh[adj[i] * 18 + fl]);
  }
  acc += __shfl_xor(acc, 32, 64);  // all 64 lanes participate
  if (act) {
    acc += __half2float(gh[node * 18 + fl]);  // self loop
    float v = fmaf(dis[node], acc, bias[fl]);
    if (half == 0) out[node * 18 + fl] = v;
  }
}

// ---------------- launch ----------------

extern "C" void kernel_launch(void* const* d_in, const int* in_sizes, int n_in,
                              void* d_out, int out_size, void* d_ws, size_t ws_size,
                              hipStream_t stream) {
  const float* x  = (const float*)d_in[0];
  const int*   ei = (const int*)d_in[1];
  const float* W1 = (const float*)d_in[2];
  const float* b1 = (const float*)d_in[3];
  const float* W2 = (const float*)d_in[4];
  const float* b2 = (const float*)d_in[5];
  const float* W3 = (const float*)d_in[6];
  const float* b3 = (const float*)d_in[7];
  const float* Wo = (const float*)d_in[8];
  const float* bo = (const float*)d_in[9];
  float* out = (float*)d_out;

  const int N = NODES;
  const int E = in_sizes[1] / 2;
  const int* rowp = ei;
  const int* colp = ei + E;

  char* p = (char*)d_ws;
  auto alloc = [&](size_t bytes) {
    void* r = (void*)p;
    p += (bytes + 255) & ~(size_t)255;
    return r;
  };
  int*   bcnt  = (int*)alloc((size_t)NBKT * 4);
  int*   bcurs = (int*)alloc((size_t)NBKT * 4);
  int*   boffs = (int*)alloc((size_t)(NBKT + 1) * 4);
  float* dis   = (float*)alloc((size_t)N * 4);
  int*   offs  = (int*)alloc((size_t)(N + 1) * 4);
  int*   adj   = (int*)alloc((size_t)E * 4);
  // recs (E*4 = 12.8MB) dead after csr_k; alias with bf16 gather table (N*64*2 = 12.8MB)
  u32*   recs  = (u32*)alloc((size_t)N * 64 * 2);
  u16*   gb    = (u16*)recs;
  float* h     = (float*)alloc((size_t)N * 64 * 4);   // fp32 hidden activations
  u16*   g4    = (u16*)alloc((size_t)N * 18 * 2);    // fp16 gather table, final layer

  zero_k<<<(NBKT + 255) / 256, 256, 0, stream>>>(bcnt, NBKT);
  bucket_hist_k<<<(E + HCHUNK - 1) / HCHUNK, 256, 0, stream>>>(colp, bcnt, E);
  bscan_k<<<1, 256, 0, stream>>>(bcnt, boffs, bcurs, NBKT, E);
  bucket_fill_k<<<(E + FCHUNK - 1) / FCHUNK, 256, 0, stream>>>(rowp, colp, bcurs, recs, E);
  csr_k<<<NBKT, 256, 0, stream>>>(recs, boffs, offs, adj, dis, N, E);

  int gG = (N + 255) / 256;
  int gA = (N + 3) / 4;

  gemm_reg_k<100, 20, 64, 1><<<gG, 256, 0, stream>>>(x, W1, dis, gb, N);
  agg_bf16_k<<<gA, 256, 0, stream>>>(gb, offs, adj, dis, b1, h, N);

  gemm_reg_k<64, 16, 64, 1><<<gG, 256, 0, stream>>>(h, W2, dis, gb, N);
  agg_bf16_k<<<gA, 256, 0, stream>>>(gb, offs, adj, dis, b2, h, N);

  gemm_reg_k<64, 16, 64, 1><<<gG, 256, 0, stream>>>(h, W3, dis, gb, N);
  agg_bf16_k<<<gA, 256, 0, stream>>>(gb, offs, adj, dis, b3, h, N);

  gemm_reg_k<64, 16, 18, 2><<<gG, 256, 0, stream>>>(h, Wo, dis, g4, N);
  agg_f16o_k<<<gA, 256, 0, stream>>>(g4, offs, adj, dis, bo, out, N);
}

// Round 9
// 439.545 us; speedup vs baseline: 1.2262x; 1.1311x over previous
//
#include <hip/hip_runtime.h>
#include <hip/hip_fp16.h>

#define NODES 100000
#define NBKT 782            // ceil(100000/128) buckets of 128 cols
#define HCHUNK 8192         // edges per bucket_hist block
#define FCHUNK 4096         // edges per bucket_fill block (256 thr x 16)

typedef unsigned short u16;
typedef unsigned int u32;

__device__ __forceinline__ float bflo(u32 v) { return __uint_as_float(v << 16); }
__device__ __forceinline__ float bfhi(u32 v) { return __uint_as_float(v & 0xFFFF0000u); }
__device__ __forceinline__ u16 f2bf(float f) {  // RNE
  u32 x = __float_as_uint(f);
  return (u16)((x + 0x7FFFu + ((x >> 16) & 1u)) >> 16);
}

// ---------------- small utils ----------------

__global__ __launch_bounds__(256) void zero_k(int* __restrict__ p, int n) {
  int i = blockIdx.x * 256 + threadIdx.x;
  if (i < n) p[i] = 0;
}

// ---------------- bucket build ----------------

__global__ __launch_bounds__(256) void bucket_hist_k(const int* __restrict__ col,
                                                     int* __restrict__ bcnt, int E) {
  __shared__ int h[NBKT];
  int t = threadIdx.x;
  for (int i = t; i < NBKT; i += 256) h[i] = 0;
  __syncthreads();
  int base = blockIdx.x * HCHUNK;
#pragma unroll 4
  for (int j = 0; j < HCHUNK / 256; ++j) {
    int i = base + j * 256 + t;
    if (i < E) atomicAdd(&h[col[i] >> 7], 1);
  }
  __syncthreads();
  for (int i = t; i < NBKT; i += 256) {
    int c = h[i];
    if (c) atomicAdd(&bcnt[i], c);
  }
}

__global__ __launch_bounds__(256) void bscan_k(const int* __restrict__ bcnt,
                                               int* __restrict__ boffs,
                                               int* __restrict__ bcurs, int nb, int E) {
  __shared__ int lds[256];
  int t = threadIdx.x;
  int base = t * 4;
  int v[4];
#pragma unroll
  for (int j = 0; j < 4; ++j) v[j] = (base + j < nb) ? bcnt[base + j] : 0;
  int s = v[0] + v[1] + v[2] + v[3];
  lds[t] = s;
  __syncthreads();
  for (int off = 1; off < 256; off <<= 1) {
    int y = (t >= off) ? lds[t - off] : 0;
    __syncthreads();
    lds[t] += y;
    __syncthreads();
  }
  int excl = lds[t] - s;
#pragma unroll
  for (int j = 0; j < 4; ++j) {
    int i = base + j;
    if (i < nb) { boffs[i] = excl; bcurs[i] = excl; }
    excl += v[j];
  }
  if (t == 255) boffs[nb] = E;
}

// scatter packed records (colLow<<17 | row) into bucket regions.
__global__ __launch_bounds__(256) void bucket_fill_k(const int* __restrict__ row,
                                                     const int* __restrict__ col,
                                                     int* __restrict__ bcurs,
                                                     u32* __restrict__ recs, int E) {
  __shared__ int lcnt[NBKT];
  __shared__ int lbase[NBKT];
  int t = threadIdx.x;
  int base = blockIdx.x * FCHUNK;
  for (int i = t; i < NBKT; i += 256) lcnt[i] = 0;
  __syncthreads();
  u32 rec[FCHUNK / 256];
  u32 meta[FCHUNK / 256];
#pragma unroll
  for (int j = 0; j < FCHUNK / 256; ++j) {
    int i = base + j * 256 + t;
    if (i < E) {
      int r = row[i], c = col[i];
      int b = c >> 7;
      rec[j] = (u32)r | ((u32)(c & 127) << 17);
      int lr = atomicAdd(&lcnt[b], 1);
      meta[j] = (u32)lr | ((u32)b << 16);
    } else {
      meta[j] = 0xFFFFFFFFu;
    }
  }
  __syncthreads();
  for (int i = t; i < NBKT; i += 256) {
    int c = lcnt[i];
    lbase[i] = c ? atomicAdd(&bcurs[i], c) : 0;
  }
  __syncthreads();
#pragma unroll
  for (int j = 0; j < FCHUNK / 256; ++j) {
    if (meta[j] != 0xFFFFFFFFu) {
      int b = meta[j] >> 16;
      int lr = meta[j] & 0xFFFF;
      recs[lbase[b] + lr] = rec[j];
    }
  }
}

// records (bucketed by col) -> per-node CSR (offs, adj) + dis. One block per bucket.
__global__ __launch_bounds__(256) void csr_k(const u32* __restrict__ recs,
                                             const int* __restrict__ boffs,
                                             int* __restrict__ offs, int* __restrict__ adj,
                                             float* __restrict__ dis, int N, int E) {
  __shared__ int cnt[128];
  __shared__ int sa[128], sb[128];
  __shared__ int cur[128];
  int b = blockIdx.x, t = threadIdx.x;
  if (t < 128) cnt[t] = 0;
  __syncthreads();
  int s = boffs[b], e = boffs[b + 1];
  for (int i = s + t; i < e; i += 256) atomicAdd(&cnt[recs[i] >> 17], 1);
  __syncthreads();
  if (t < 128) sa[t] = cnt[t];
  __syncthreads();
#pragma unroll
  for (int off = 1; off < 128; off <<= 1) {
    if (t < 128) sb[t] = sa[t] + ((t >= off) ? sa[t - off] : 0);
    __syncthreads();
    if (t < 128) sa[t] = sb[t];
    __syncthreads();
  }
  if (t < 128) {
    int c = b * 128 + t;
    if (c < N) {
      int excl = sa[t] - cnt[t];
      offs[c] = s + excl;
      cur[t] = s + excl;
      dis[c] = rsqrtf((float)(cnt[t] + 1));  // +1 self loop
    }
  }
  if (b == 0 && t == 0) offs[N] = E;
  __syncthreads();
  for (int i = s + t; i < e; i += 256) {
    u32 r = recs[i];
    int p = atomicAdd(&cur[r >> 17], 1);
    adj[p] = (int)(r & 0x1FFFF);
  }
}

// ---------------- GEMM (NOUT=64): G[node,:] = (X[node,:] @ W) * dis[node] ----------------
// 4 threads/node (q = t&3 owns outs [16q,16q+16)), 2 nodes/thread (g, g+64).
// Lane holds contiguous K/4 slice of x-row in regs; quad-mates get it via __shfl(.,qq,4).
// W staged fp32 in LDS; per-k 4x ds_read_b128 (2-way conflict = free), 16 W vals / 32 FMA.
// OUTFMT: 1 = bf16 out, 2 = fp16 out.
template <int K, int NK, int OUTFMT>
__global__ __launch_bounds__(256, 2) void gemm64_k(const float* __restrict__ X,
                                                   const float* __restrict__ W,
                                                   const float* __restrict__ dis,
                                                   u16* __restrict__ G, int n) {
  static_assert(K == NK * 4, "NT=4");
  __shared__ float ws[K * 64];
  int t = threadIdx.x;
  for (int i = t; i < K * 64; i += 256) ws[i] = W[i];
  __syncthreads();
  int q = t & 3, g = t >> 2;
  int b0 = blockIdx.x * 128;
  int n0 = b0 + g, n1 = b0 + 64 + g;
  int c0 = (n0 < n) ? n0 : 0, c1 = (n1 < n) ? n1 : 0;
  float xv0[NK], xv1[NK];
  const float* p0 = X + (size_t)c0 * K + q * NK;
  const float* p1 = X + (size_t)c1 * K + q * NK;
  if constexpr (NK % 4 == 0) {
#pragma unroll
    for (int i = 0; i < NK / 4; ++i) {
      *(float4*)&xv0[4 * i] = *(const float4*)(p0 + 4 * i);
      *(float4*)&xv1[4 * i] = *(const float4*)(p1 + 4 * i);
    }
  } else {
#pragma unroll
    for (int i = 0; i < NK; ++i) { xv0[i] = p0[i]; xv1[i] = p1[i]; }
  }
  float acc0[16], acc1[16];
#pragma unroll
  for (int j = 0; j < 16; ++j) { acc0[j] = 0.f; acc1[j] = 0.f; }
  for (int qq = 0; qq < 4; ++qq) {  // runtime owner loop keeps code size sane
    const float* wbase = ws + (size_t)qq * NK * 64 + q * 16;
#pragma unroll
    for (int i = 0; i < NK; ++i) {
      float a0 = __shfl(xv0[i], qq, 4);
      float a1 = __shfl(xv1[i], qq, 4);
      const float* wr = wbase + i * 64;
#pragma unroll
      for (int j = 0; j < 16; ++j) {
        float w = wr[j];
        acc0[j] = fmaf(a0, w, acc0[j]);
        acc1[j] = fmaf(a1, w, acc1[j]);
      }
    }
  }
  // epilogue: scale, pack 2B, store 32B (2 x uint4) per node per lane
  uint4* G4 = (uint4*)G;  // row = 128B = 8 x uint4; lane q covers words [2q, 2q+2)
  {
    if (n0 < n) {
      float sc = dis[n0];
      u32 os[8];
#pragma unroll
      for (int j = 0; j < 8; ++j) {
        float v0 = acc0[2 * j] * sc, v1 = acc0[2 * j + 1] * sc;
        u16 lo = (OUTFMT == 1) ? f2bf(v0) : __half_as_ushort(__float2half(v0));
        u16 hi = (OUTFMT == 1) ? f2bf(v1) : __half_as_ushort(__float2half(v1));
        os[j] = (u32)lo | ((u32)hi << 16);
      }
      size_t rb = (size_t)n0 * 8 + q * 2;
      G4[rb]     = make_uint4(os[0], os[1], os[2], os[3]);
      G4[rb + 1] = make_uint4(os[4], os[5], os[6], os[7]);
    }
    if (n1 < n) {
      float sc = dis[n1];
      u32 os[8];
#pragma unroll
      for (int j = 0; j < 8; ++j) {
        float v0 = acc1[2 * j] * sc, v1 = acc1[2 * j + 1] * sc;
        u16 lo = (OUTFMT == 1) ? f2bf(v0) : __half_as_ushort(__float2half(v0));
        u16 hi = (OUTFMT == 1) ? f2bf(v1) : __half_as_ushort(__float2half(v1));
        os[j] = (u32)lo | ((u32)hi << 16);
      }
      size_t rb = (size_t)n1 * 8 + q * 2;
      G4[rb]     = make_uint4(os[0], os[1], os[2], os[3]);
      G4[rb + 1] = make_uint4(os[4], os[5], os[6], os[7]);
    }
  }
}

// ---------------- GEMM (final, NOUT=18, fp16 out): 2 threads/node, outs split 10/8 ----------------
__global__ __launch_bounds__(256, 2) void gemm18_k(const float* __restrict__ X,  // K=64
                                                   const float* __restrict__ W,
                                                   const float* __restrict__ dis,
                                                   u16* __restrict__ G, int n) {
  __shared__ float ws[64 * 18];
  int t = threadIdx.x;
  for (int i = t; i < 64 * 18; i += 256) ws[i] = W[i];
  __syncthreads();
  int q = t & 1, g = t >> 1;  // g in [0,128)
  int b0 = blockIdx.x * 128;
  int node = b0 + g;
  int cn = (node < n) ? node : 0;
  float xv[32];
  const float* p = X + (size_t)cn * 64 + q * 32;
#pragma unroll
  for (int i = 0; i < 8; ++i) *(float4*)&xv[4 * i] = *(const float4*)(p + 4 * i);
  int cnt = q ? 8 : 10;        // q0: outs [0,10), q1: outs [10,18)
  float acc[10];
#pragma unroll
  for (int j = 0; j < 10; ++j) acc[j] = 0.f;
  for (int qq = 0; qq < 2; ++qq) {
    const float* wbase = ws + (size_t)qq * 32 * 18 + q * 10;
#pragma unroll
    for (int i = 0; i < 32; ++i) {
      float a = __shfl(xv[i], qq, 2);
      const float* wr = wbase + i * 18;
#pragma unroll
      for (int j = 0; j < 10; ++j)
        if (j < cnt) acc[j] = fmaf(a, wr[j], acc[j]);
    }
  }
  if (node >= n) return;
  float sc = dis[node];
  u32* G32 = (u32*)G;  // row = 9 u32; q0 -> words 0..4, q1 -> words 5..8
  if (q == 0) {
    u32 os[5];
#pragma unroll
    for (int j = 0; j < 5; ++j) {
      u16 lo = __half_as_ushort(__float2half(acc[2 * j] * sc));
      u16 hi = __half_as_ushort(__float2half(acc[2 * j + 1] * sc));
      os[j] = (u32)lo | ((u32)hi << 16);
    }
#pragma unroll
    for (int j = 0; j < 5; ++j) G32[(size_t)node * 9 + j] = os[j];
  } else {
    u32 os[4];
#pragma unroll
    for (int j = 0; j < 4; ++j) {
      u16 lo = __half_as_ushort(__float2half(acc[2 * j] * sc));
      u16 hi = __half_as_ushort(__float2half(acc[2 * j + 1] * sc));
      os[j] = (u32)lo | ((u32)hi << 16);
    }
#pragma unroll
    for (int j = 0; j < 4; ++j) G32[(size_t)node * 9 + 5 + j] = os[j];
  }
}

// ---------------- aggregation (hidden): 2 edges per wave-gather, 16 edges in flight ----------------
__global__ __launch_bounds__(256) void agg_bf16_k(const u16* __restrict__ g,
                                                  const int* __restrict__ offs,
                                                  const int* __restrict__ adj,
                                                  const float* __restrict__ dis,
                                                  const float* __restrict__ bias,
                                                  float* __restrict__ out, int n) {
  int node = blockIdx.x * 4 + (threadIdx.x >> 6);
  int lane = threadIdx.x & 63;
  int half = lane >> 5, fl = lane & 31;
  if (node >= n) return;
  const u32* g32 = (const u32*)g;
  float acc0 = 0.f, acc1 = 0.f;
  int s = offs[node], e = offs[node + 1];
  int i = s;
  for (; i + 16 <= e; i += 16) {  // 8 gathers in flight per lane
    int r0 = adj[i + half];
    int r1 = adj[i + 2 + half];
    int r2 = adj[i + 4 + half];
    int r3 = adj[i + 6 + half];
    int r4 = adj[i + 8 + half];
    int r5 = adj[i + 10 + half];
    int r6 = adj[i + 12 + half];
    int r7 = adj[i + 14 + half];
    u32 v0 = g32[(r0 << 5) + fl];
    u32 v1 = g32[(r1 << 5) + fl];
    u32 v2 = g32[(r2 << 5) + fl];
    u32 v3 = g32[(r3 << 5) + fl];
    u32 v4 = g32[(r4 << 5) + fl];
    u32 v5 = g32[(r5 << 5) + fl];
    u32 v6 = g32[(r6 << 5) + fl];
    u32 v7 = g32[(r7 << 5) + fl];
    acc0 += ((bflo(v0) + bflo(v1)) + (bflo(v2) + bflo(v3))) +
            ((bflo(v4) + bflo(v5)) + (bflo(v6) + bflo(v7)));
    acc1 += ((bfhi(v0) + bfhi(v1)) + (bfhi(v2) + bfhi(v3))) +
            ((bfhi(v4) + bfhi(v5)) + (bfhi(v6) + bfhi(v7)));
  }
  for (; i + 8 <= e; i += 8) {
    int r0 = adj[i + half];
    int r1 = adj[i + 2 + half];
    int r2 = adj[i + 4 + half];
    int r3 = adj[i + 6 + half];
    u32 v0 = g32[(r0 << 5) + fl];
    u32 v1 = g32[(r1 << 5) + fl];
    u32 v2 = g32[(r2 << 5) + fl];
    u32 v3 = g32[(r3 << 5) + fl];
    acc0 += (bflo(v0) + bflo(v1)) + (bflo(v2) + bflo(v3));
    acc1 += (bfhi(v0) + bfhi(v1)) + (bfhi(v2) + bfhi(v3));
  }
  for (; i + 2 <= e; i += 2) {
    int r = adj[i + half];
    u32 v = g32[(r << 5) + fl];
    acc0 += bflo(v);
    acc1 += bfhi(v);
  }
  if (i < e) {  // odd tail edge: only half 0 counts it
    int r = adj[i];
    u32 v = g32[(r << 5) + fl];
    if (half == 0) { acc0 += bflo(v); acc1 += bfhi(v); }
  }
  acc0 += __shfl_xor(acc0, 32, 64);
  acc1 += __shfl_xor(acc1, 32, 64);
  u32 vs = g32[(node << 5) + fl];  // self loop (pre-scaled by dis[node])
  acc0 += bflo(vs);
  acc1 += bfhi(vs);
  float d = dis[node];
  float o0 = fmaxf(fmaf(d, acc0, bias[2 * fl]), 0.f);
  float o1 = fmaxf(fmaf(d, acc1, bias[2 * fl + 1]), 0.f);
  if (half == 0) {
    float2 st = {o0, o1};
    *(float2*)(out + node * 64 + 2 * fl) = st;
  }
}

// ---------------- aggregation (final, 18-wide fp16 table): 2 edges/gather, 16 in flight ----------------
__global__ __launch_bounds__(256) void agg_f16o_k(const u16* __restrict__ g,
                                                  const int* __restrict__ offs,
                                                  const int* __restrict__ adj,
                                                  const float* __restrict__ dis,
                                                  const float* __restrict__ bias,
                                                  float* __restrict__ out, int n) {
  int node = blockIdx.x * 4 + (threadIdx.x >> 6);
  int lane = threadIdx.x & 63;
  int half = lane >> 5, fl = lane & 31;
  if (node >= n) return;
  const __half* gh = (const __half*)g;
  bool act = fl < 18;
  float acc = 0.f;
  int s = offs[node], e = offs[node + 1];
  int i = s;
  if (act) {
    for (; i + 16 <= e; i += 16) {
      int r0 = adj[i + half];
      int r1 = adj[i + 2 + half];
      int r2 = adj[i + 4 + half];
      int r3 = adj[i + 6 + half];
      int r4 = adj[i + 8 + half];
      int r5 = adj[i + 10 + half];
      int r6 = adj[i + 12 + half];
      int r7 = adj[i + 14 + half];
      float a0 = __half2float(gh[r0 * 18 + fl]);
      float a1 = __half2float(gh[r1 * 18 + fl]);
      float a2 = __half2float(gh[r2 * 18 + fl]);
      float a3 = __half2float(gh[r3 * 18 + fl]);
      float a4 = __half2float(gh[r4 * 18 + fl]);
      float a5 = __half2float(gh[r5 * 18 + fl]);
      float a6 = __half2float(gh[r6 * 18 + fl]);
      float a7 = __half2float(gh[r7 * 18 + fl]);
      acc += ((a0 + a1) + (a2 + a3)) + ((a4 + a5) + (a6 + a7));
    }
    for (; i + 8 <= e; i += 8) {
      int r0 = adj[i + half];
      int r1 = adj[i + 2 + half];
      int r2 = adj[i + 4 + half];
      int r3 = adj[i + 6 + half];
      float a0 = __half2float(gh[r0 * 18 + fl]);
      float a1 = __half2float(gh[r1 * 18 + fl]);
      float a2 = __half2float(gh[r2 * 18 + fl]);
      float a3 = __half2float(gh[r3 * 18 + fl]);
      acc += (a0 + a1) + (a2 + a3);
    }
    for (; i + 2 <= e; i += 2) acc += __half2float(gh[adj[i + half] * 18 + fl]);
    if (i < e && half == 0) acc += __half2float(gh[adj[i] * 18 + fl]);
  }
  acc += __shfl_xor(acc, 32, 64);  // all 64 lanes participate
  if (act) {
    acc += __half2float(gh[node * 18 + fl]);  // self loop
    float v = fmaf(dis[node], acc, bias[fl]);
    if (half == 0) out[node * 18 + fl] = v;
  }
}

// ---------------- launch ----------------

extern "C" void kernel_launch(void* const* d_in, const int* in_sizes, int n_in,
                              void* d_out, int out_size, void* d_ws, size_t ws_size,
                              hipStream_t stream) {
  const float* x  = (const float*)d_in[0];
  const int*   ei = (const int*)d_in[1];
  const float* W1 = (const float*)d_in[2];
  const float* b1 = (const float*)d_in[3];
  const float* W2 = (const float*)d_in[4];
  const float* b2 = (const float*)d_in[5];
  const float* W3 = (const float*)d_in[6];
  const float* b3 = (const float*)d_in[7];
  const float* Wo = (const float*)d_in[8];
  const float* bo = (const float*)d_in[9];
  float* out = (float*)d_out;

  const int N = NODES;
  const int E = in_sizes[1] / 2;
  const int* rowp = ei;
  const int* colp = ei + E;

  char* p = (char*)d_ws;
  auto alloc = [&](size_t bytes) {
    void* r = (void*)p;
    p += (bytes + 255) & ~(size_t)255;
    return r;
  };
  int*   bcnt  = (int*)alloc((size_t)NBKT * 4);
  int*   bcurs = (int*)alloc((size_t)NBKT * 4);
  int*   boffs = (int*)alloc((size_t)(NBKT + 1) * 4);
  float* dis   = (float*)alloc((size_t)N * 4);
  int*   offs  = (int*)alloc((size_t)(N + 1) * 4);
  int*   adj   = (int*)alloc((size_t)E * 4);
  // recs (E*4 = 12.8MB) dead after csr_k; alias with bf16 gather table (N*64*2 = 12.8MB)
  u32*   recs  = (u32*)alloc((size_t)N * 64 * 2);
  u16*   gb    = (u16*)recs;
  float* h     = (float*)alloc((size_t)N * 64 * 4);   // fp32 hidden activations
  u16*   g4    = (u16*)alloc((size_t)N * 18 * 2);    // fp16 gather table, final layer

  zero_k<<<(NBKT + 255) / 256, 256, 0, stream>>>(bcnt, NBKT);
  bucket_hist_k<<<(E + HCHUNK - 1) / HCHUNK, 256, 0, stream>>>(colp, bcnt, E);
  bscan_k<<<1, 256, 0, stream>>>(bcnt, boffs, bcurs, NBKT, E);
  bucket_fill_k<<<(E + FCHUNK - 1) / FCHUNK, 256, 0, stream>>>(rowp, colp, bcurs, recs, E);
  csr_k<<<NBKT, 256, 0, stream>>>(recs, boffs, offs, adj, dis, N, E);

  int gG = (N + 127) / 128;   // 128 nodes per gemm block
  int gA = (N + 3) / 4;

  gemm64_k<100, 25, 1><<<gG, 256, 0, stream>>>(x, W1, dis, gb, N);
  agg_bf16_k<<<gA, 256, 0, stream>>>(gb, offs, adj, dis, b1, h, N);

  gemm64_k<64, 16, 1><<<gG, 256, 0, stream>>>(h, W2, dis, gb, N);
  agg_bf16_k<<<gA, 256, 0, stream>>>(gb, offs, adj, dis, b2, h, N);

  gemm64_k<64, 16, 1><<<gG, 256, 0, stream>>>(h, W3, dis, gb, N);
  agg_bf16_k<<<gA, 256, 0, stream>>>(gb, offs, adj, dis, b3, h, N);

  gemm18_k<<<gG, 256, 0, stream>>>(h, Wo, dis, g4, N);
  agg_f16o_k<<<gA, 256, 0, stream>>>(g4, offs, adj, dis, bo, out, N);
}